// Round 8
// baseline (179.374 us; speedup 1.0000x reference)
//
#include <hip/hip_runtime.h>
#include <hip/hip_bf16.h>

// Problem constants
#define B_    4
#define CI_   64
#define CO_   128
#define NIN_  65536
#define NOUT_ 16384
#define KK_   9
#define PP_   4
#define HH_   32

typedef _Float16 f16x8 __attribute__((ext_vector_type(8)));
typedef _Float16 f16x4 __attribute__((ext_vector_type(4)));
typedef float    f32x4 __attribute__((ext_vector_type(4)));

// ---------------- small kernels ----------------

__global__ void zero_kernel(float* p, int n) {
    int i = blockIdx.x * 256 + threadIdx.x;
    if (i < n) p[i] = 0.f;
}

// a[m,k] = weight_net(off[m,k,:2]) for both off1 and off2
__global__ void wnet_kernel(const float* __restrict__ off1, const float* __restrict__ off2,
                            const float* __restrict__ w1, const float* __restrict__ b1,
                            const float* __restrict__ w2, const float* __restrict__ b2,
                            float* __restrict__ a1, float* __restrict__ a2) {
    int idx = blockIdx.x * 256 + threadIdx.x;
    if (idx >= NOUT_ * KK_) return;
    float x0 = off1[idx*2+0], x1 = off1[idx*2+1];
    float y0 = off2[idx*2+0], y1 = off2[idx*2+1];
    float bias2 = b2[0];
    float s1 = bias2, s2 = bias2;
    #pragma unroll
    for (int h = 0; h < HH_; ++h) {
        float wh0 = w1[h], wh1 = w1[HH_+h], bh = b1[h], vh = w2[h];
        s1 += fmaxf(x0*wh0 + x1*wh1 + bh, 0.f) * vh;
        s2 += fmaxf(y0*wh0 + y1*wh1 + bh, 0.f) * vh;
    }
    a1[idx] = s1;
    a2[idx] = s2;
}

// Pack W into per-lane MFMA A-fragment order (fp16).
// Wf chunk index g = (CIN/32)*k + kap; element f = ((g*8 + ot)*64 + l)*8 + j holds
//   A[o = ot*16 + (l&15)][ch = kap*32 + ((l>>4)&3)*8 + j] of kernel-tap k.
template<int CIN>
__global__ void wpack_kernel(const float* __restrict__ W, _Float16* __restrict__ Wf) {
    constexpr int NSLAB = (CIN/64) * KK_;
    int f = blockIdx.x * 256 + threadIdx.x;
    if (f >= NSLAB * 8192) return;
    int j   = f & 7;
    int l   = (f >> 3) & 63;
    int ot  = (f >> 9) & 7;
    int kap = (f >> 12) & 1;
    int s   = f >> 13;
    int o   = ot*16 + (l & 15);
    int kel = kap*32 + ((l >> 4) & 3)*8 + j;
    int k, i;
    if (CIN == 64) { k = s; i = kel; }
    else           { k = s >> 1; i = ((s & 1) << 6) + kel; }
    Wf[f] = (_Float16)W[((size_t)o*CIN + i)*KK_ + k];
}

// Pack exp_w [128][64] into A-fragment order (single slab, mirrors wpack s=0)
__global__ void epack_kernel(const float* __restrict__ E, _Float16* __restrict__ Ef) {
    int f = blockIdx.x * 256 + threadIdx.x;
    if (f >= 8192) return;
    int j   = f & 7;
    int l   = (f >> 3) & 63;
    int ot  = (f >> 9) & 7;
    int kap = (f >> 12) & 1;
    int o   = ot*16 + (l & 15);
    int i   = kap*32 + ((l >> 4) & 3)*8 + j;
    Ef[f] = (_Float16)E[o*64 + i];
}

// xT[p][b][i] (fp16) = x[b][i][p] (f32)
__global__ void xtrans_kernel(const float* __restrict__ x, _Float16* __restrict__ xT) {
    __shared__ float tile[64][65];
    int p0 = blockIdx.x * 64;
    int b  = blockIdx.y;
    int t  = threadIdx.x;
    #pragma unroll
    for (int r = 0; r < 16; ++r) {
        int f = r*256 + t;
        int i = f >> 6, pp = f & 63;
        tile[i][pp] = x[((size_t)(b*CI_ + i))*NIN_ + p0 + pp];
    }
    __syncthreads();
    #pragma unroll
    for (int r = 0; r < 2; ++r) {    // vectorized f16x8 stores
        int f  = r*256 + t;          // f in [0,512)
        int pp = f >> 3;
        int i0 = (f & 7) * 8;
        f16x8 v;
        #pragma unroll
        for (int e = 0; e < 8; ++e) v[e] = (_Float16)tile[i0+e][pp];
        *(f16x8*)(xT + ((size_t)(p0+pp)*B_ + b)*CI_ + i0) = v;
    }
}

// stage-2 stat reduce: 32 blocks x 32 source blocks -> 32 low-contention atomics/addr
__global__ __launch_bounds__(256) void bnreduce_kernel(const float* __restrict__ pbuf,
                                                       float* __restrict__ stats) {
    int t = threadIdx.x;
    float s = 0.f;
    int base = blockIdx.x * 32;
    #pragma unroll
    for (int b = 0; b < 32; ++b)
        s += pbuf[(size_t)(base + b)*256 + t];
    atomicAdd(&stats[t], s);
}

// accumulated sums -> scale / (bias + extra_bias)   (extra_bias folds exp_b for BN2)
__global__ void bnparams_kernel(const float* __restrict__ gsum, const float* __restrict__ gsq,
                                const float* __restrict__ g, const float* __restrict__ bb,
                                const float* __restrict__ eb,
                                float* __restrict__ scbi) {
    int o = threadIdx.x;  // 128 threads
    const float inv_n = 1.f / (B_ * NOUT_);
    float mean = gsum[o] * inv_n;
    float var  = gsq[o] * inv_n - mean*mean;
    float sc   = g[o] * rsqrtf(var + 1e-5f);
    scbi[o]       = sc;
    scbi[128 + o] = bb[o] - mean*sc + eb[o];
}

// ---------------- MFMA conv (implicit GEMM, gather-staged, pipelined) ----------------
// out[n][o] = sum_{k,i} W[o,i,k] * a[m,k] * bnrelu?(in[nbr[m,k]*B+b][i]),  n = mi*4+b.
// Block: 128 o x 64 n (16 m), grid 1024.  Slab = full input row (K=CIN), 9 slabs,
// double-buffered LDS, ONE barrier per slab:
//   { write LDS[s&1] <- regs ; barrier ; issue gather loads s+1 ; MFMA from LDS[s&1] }
// BN template: conv2 applies BN1+ReLU (per-channel, fp16) during staging — this
// deletes the standalone bnrelu pass. Conv is L2-fill-bound (R5/R6/R7: FETCH~60MB
// @ ~1.3TB/s regardless of structure), so the extra VALU is hidden.
template<int CIN, bool BN>
__global__ __launch_bounds__(256, CIN == 64 ? 4 : 3) void conv_mfma_kernel(
    const _Float16* __restrict__ in,    // [Npts*B][CIN]
    const _Float16* __restrict__ Wf,    // frag-packed fp16
    const int*      __restrict__ nbr,   // [NOUT][K]
    const float*    __restrict__ amk,   // [NOUT][K]
    const float*    __restrict__ bnscbi,// [128] scale | [128] bias (BN only)
    _Float16*       __restrict__ outh,  // [NOUT*B][128] raw (pre-BN)
    float*          __restrict__ pbuf)  // [grid][256] partial sums/sumsq
{
    constexpr int NKAP = CIN/32;        // MFMA K-groups per slab / f16x8 loads per thread
    __shared__ _Float16 Gs[2][64*CIN];  // XOR-swizzled: chunk ^= row&7
    const int t    = threadIdx.x;
    const int lane = t & 63;
    const int wid  = t >> 6;
    const int wr   = wid >> 1, wc = wid & 1;
    const int m0   = blockIdx.x * 16;
    const int l15 = lane & 15, l4 = lane >> 4, l7 = lane & 7;
    // staging assignment: thread -> (row n, quarter sq)
    const int srow = t >> 2;            // n = mi*4 + b
    const int sq   = t & 3;
    const int sb   = srow & 3;
    const int sm   = m0 + (srow >> 2);

    // preload gather indices + interpolation weights (hoists dependent chain)
    int   pn[KK_];
    float pa[KK_];
    #pragma unroll
    for (int k = 0; k < KK_; ++k) { pn[k] = nbr[sm*KK_ + k]; pa[k] = amk[sm*KK_ + k]; }

    // per-thread BN scale/bias (fp16) for this thread's channel quarter
    f16x8 sc16[NKAP], bi16[NKAP];
    if constexpr (BN) {
        #pragma unroll
        for (int q = 0; q < NKAP; ++q)
            #pragma unroll
            for (int e = 0; e < 8; ++e) {
                int i = sq*(CIN/4) + q*8 + e;
                sc16[q][e] = (_Float16)bnscbi[i];
                bi16[q][e] = (_Float16)bnscbi[128 + i];
            }
    }

    f32x4 acc[4][2];
    #pragma unroll
    for (int c = 0; c < 4; ++c)
        #pragma unroll
        for (int j = 0; j < 2; ++j)
            acc[c][j] = (f32x4){0.f, 0.f, 0.f, 0.f};

    // prologue: gather slab 0 into regs
    f16x8 greg[NKAP];
    {
        const _Float16* src = in + ((size_t)pn[0]*B_ + sb)*CIN + sq*(CIN/4);
        #pragma unroll
        for (int q = 0; q < NKAP; ++q) greg[q] = *(const f16x8*)(src + q*8);
    }

    #pragma unroll
    for (int s = 0; s < KK_; ++s) {
        // (bn+relu) + a-scale + write LDS[s&1]
        const _Float16 hs = (_Float16)pa[s];
        #pragma unroll
        for (int q = 0; q < NKAP; ++q) {
            f16x8 v = greg[q];
            if constexpr (BN) {
                #pragma unroll
                for (int e = 0; e < 8; ++e) {
                    _Float16 f = v[e]*sc16[q][e] + bi16[q][e];
                    v[e] = (f > (_Float16)0.f ? f : (_Float16)0.f) * hs;
                }
            } else {
                #pragma unroll
                for (int e = 0; e < 8; ++e) v[e] = v[e] * hs;
            }
            const int c4 = sq*NKAP + q;
            *(f16x8*)(&Gs[s&1][srow*CIN + ((c4 ^ (srow & 7)) << 3)]) = v;
        }
        __syncthreads();
        // issue next slab's gather (latency hides under MFMA below)
        f16x8 gn[NKAP];
        if (s + 1 < KK_) {
            const _Float16* src = in + ((size_t)pn[s+1]*B_ + sb)*CIN + sq*(CIN/4);
            #pragma unroll
            for (int q = 0; q < NKAP; ++q) gn[q] = *(const f16x8*)(src + q*8);
        }
        // compute: A-frags from global (L2-hot), B from LDS
        #pragma unroll
        for (int kap = 0; kap < NKAP; ++kap) {
            f16x8 aF[4], bF[2];
            const _Float16* wbase = Wf + ((size_t)(s*NKAP + kap)*8*64)*8;
            #pragma unroll
            for (int c = 0; c < 4; ++c)
                aF[c] = *(const f16x8*)(wbase + (((wr*4 + c)*64 + lane) << 3));
            #pragma unroll
            for (int jt = 0; jt < 2; ++jt) {
                const int row = wc*32 + jt*16 + l15;
                const int ch  = (kap*4 + l4) ^ l7;   // row&7 == l7
                bF[jt] = *(const f16x8*)(&Gs[s&1][row*CIN + (ch << 3)]);
            }
            #pragma unroll
            for (int c = 0; c < 4; ++c)
                #pragma unroll
                for (int jt = 0; jt < 2; ++jt)
                    acc[c][jt] = __builtin_amdgcn_mfma_f32_16x16x32_f16(
                        aF[c], bF[jt], acc[c][jt], 0, 0, 0);
        }
        if (s + 1 < KK_) {
            #pragma unroll
            for (int q = 0; q < NKAP; ++q) greg[q] = gn[q];
        }
    }

    // ---- in-register BN statistics -> per-block partial (deterministic) ----
    // element at (o = wr*64 + c*16 + l4*4 + r,  n = wc*32 + jt*16 + l15)
    __syncthreads();                 // all waves done reading Gs
    float* red = (float*)Gs;         // [wc][stat][128 o] = 512 floats
    #pragma unroll
    for (int c = 0; c < 4; ++c) {
        #pragma unroll
        for (int r = 0; r < 4; ++r) {
            float s = acc[c][0][r] + acc[c][1][r];
            float q = acc[c][0][r]*acc[c][0][r] + acc[c][1][r]*acc[c][1][r];
            #pragma unroll
            for (int msk = 1; msk <= 8; msk <<= 1) {
                s += __shfl_xor(s, msk);
                q += __shfl_xor(q, msk);
            }
            if (l15 == 0) {
                const int o = wr*64 + c*16 + l4*4 + r;
                red[wc*256 + o]       = s;
                red[wc*256 + 128 + o] = q;
            }
        }
    }
    __syncthreads();
    pbuf[(size_t)blockIdx.x*256 + t] = red[t] + red[256 + t];  // coalesced 1KB
    // epilogue: direct fp16 store (D: col=lane&15, row=(lane>>4)*4+reg)
    #pragma unroll
    for (int c = 0; c < 4; ++c) {
        const int o = wr*64 + c*16 + l4*4;
        #pragma unroll
        for (int jt = 0; jt < 2; ++jt) {
            const int n = wc*32 + jt*16 + l15;
            f16x4 h;
            #pragma unroll
            for (int r = 0; r < 4; ++r) h[r] = (_Float16)acc[c][jt][r];
            *(f16x4*)(outh + ((size_t)(m0*B_) + n)*CO_ + o) = h;
        }
    }
}

// ---------------- final: MFMA identity GEMM + BN2 + add + relu ----------------
__global__ __launch_bounds__(256, 4) void final_mfma_kernel(
    const _Float16* __restrict__ xh,      // [NIN*B][64]
    const _Float16* __restrict__ out2T,   // [NOUT*B][128] raw (pre-BN)
    const int*      __restrict__ pool_idx,// [NOUT][4]
    const _Float16* __restrict__ Ef,      // frag-packed exp_w
    const float*    __restrict__ scbi2,   // sc[128] | (bi+exp_b)[128]
    float*          __restrict__ out)     // [B][128][NOUT]
{
    __shared__ _Float16 Gs[64*64];        // XOR-swizzled pooled tile
    const int t    = threadIdx.x;
    const int lane = t & 63;
    const int wid  = t >> 6;
    const int wr   = wid >> 1, wc = wid & 1;
    const int m0   = blockIdx.x * 16;
    const int l15 = lane & 15, l4 = lane >> 4, l7 = lane & 7;

    // ---- staging: pooled rows, vectorized f16x8 gather ----
    {
        const int srow = t >> 2;          // n = b*16 + mi
        const int sq   = t & 3;           // 16-element quarter
        const int m    = m0 + (srow & 15);
        const int b    = srow >> 4;
        const int4 pidx = *(const int4*)(pool_idx + m*4);
        const _Float16* r0 = xh + ((size_t)pidx.x*B_ + b)*CI_ + sq*16;
        const _Float16* r1 = xh + ((size_t)pidx.y*B_ + b)*CI_ + sq*16;
        const _Float16* r2 = xh + ((size_t)pidx.z*B_ + b)*CI_ + sq*16;
        const _Float16* r3 = xh + ((size_t)pidx.w*B_ + b)*CI_ + sq*16;
        #pragma unroll
        for (int q = 0; q < 2; ++q) {
            f16x8 v  = *(const f16x8*)(r0 + q*8);
            f16x8 v1 = *(const f16x8*)(r1 + q*8);
            f16x8 v2 = *(const f16x8*)(r2 + q*8);
            f16x8 v3 = *(const f16x8*)(r3 + q*8);
            v = v + v1 + v2 + v3;
            #pragma unroll
            for (int e = 0; e < 8; ++e) v[e] = v[e] * (_Float16)0.25f;
            const int c4 = sq*2 + q;
            *(f16x8*)(Gs + srow*64 + ((c4 ^ (srow & 7)) << 3)) = v;
        }
    }
    __syncthreads();

    // ---- MFMA: identity = exp_w @ pooled ----
    f32x4 acc[4][2];
    #pragma unroll
    for (int c = 0; c < 4; ++c)
        #pragma unroll
        for (int j = 0; j < 2; ++j)
            acc[c][j] = (f32x4){0.f, 0.f, 0.f, 0.f};
    #pragma unroll
    for (int kap = 0; kap < 2; ++kap) {
        f16x8 aF[4], bF[2];
        #pragma unroll
        for (int c = 0; c < 4; ++c)
            aF[c] = *(const f16x8*)(Ef + ((size_t)((kap*8 + wr*4 + c)*64 + lane))*8);
        #pragma unroll
        for (int jt = 0; jt < 2; ++jt) {
            const int row = wc*32 + jt*16 + l15;
            const int ch  = (kap*4 + l4) ^ l7;
            bF[jt] = *(const f16x8*)(Gs + row*64 + (ch << 3));
        }
        #pragma unroll
        for (int c = 0; c < 4; ++c)
            #pragma unroll
            for (int jt = 0; jt < 2; ++jt)
                acc[c][jt] = __builtin_amdgcn_mfma_f32_16x16x32_f16(
                    aF[c], bF[jt], acc[c][jt], 0, 0, 0);
    }

    // ---- epilogue: BN2(out2T) + identity + relu -> out[b][o][m] ----
    const int m = m0 + l15;
    #pragma unroll
    for (int c = 0; c < 4; ++c) {
        const int o = wr*64 + c*16 + l4*4;
        const float4 sc4 = *(const float4*)(scbi2 + o);
        const float4 bi4 = *(const float4*)(scbi2 + 128 + o);
        #pragma unroll
        for (int jt = 0; jt < 2; ++jt) {
            const int b = wc*2 + jt;     // n = wc*32+jt*16+l15 -> b = n>>4
            const f16x4 v2 = *(const f16x4*)(out2T + ((size_t)(m*B_ + b))*CO_ + o);
            float res0 = fmaxf(acc[c][jt][0] + (float)v2[0]*sc4.x + bi4.x, 0.f);
            float res1 = fmaxf(acc[c][jt][1] + (float)v2[1]*sc4.y + bi4.y, 0.f);
            float res2 = fmaxf(acc[c][jt][2] + (float)v2[2]*sc4.z + bi4.z, 0.f);
            float res3 = fmaxf(acc[c][jt][3] + (float)v2[3]*sc4.w + bi4.w, 0.f);
            out[((size_t)(b*CO_ + o + 0))*NOUT_ + m] = res0;
            out[((size_t)(b*CO_ + o + 1))*NOUT_ + m] = res1;
            out[((size_t)(b*CO_ + o + 2))*NOUT_ + m] = res2;
            out[((size_t)(b*CO_ + o + 3))*NOUT_ + m] = res3;
        }
    }
}

// ---------------- launch ----------------
extern "C" void kernel_launch(void* const* d_in, const int* in_sizes, int n_in,
                              void* d_out, int out_size, void* d_ws, size_t ws_size,
                              hipStream_t stream) {
    const float* x        = (const float*)d_in[0];
    const float* off1     = (const float*)d_in[1];
    const float* off2     = (const float*)d_in[2];
    const int*   nbr1     = (const int*)  d_in[3];
    const int*   nbr2     = (const int*)  d_in[4];
    const int*   pool_idx = (const int*)  d_in[5];
    const float* wn_w1    = (const float*)d_in[6];
    const float* wn_b1    = (const float*)d_in[7];
    const float* wn_w2    = (const float*)d_in[8];
    const float* wn_b2    = (const float*)d_in[9];
    const float* W1       = (const float*)d_in[10];
    const float* W2       = (const float*)d_in[11];
    const float* bn1_g    = (const float*)d_in[12];
    const float* bn1_b    = (const float*)d_in[13];
    const float* bn2_g    = (const float*)d_in[14];
    const float* bn2_b    = (const float*)d_in[15];
    const float* exp_w    = (const float*)d_in[16];
    const float* exp_b    = (const float*)d_in[17];
    float* out = (float*)d_out;

    // workspace carve (~69 MB)
    char* ws = (char*)d_ws;
    float* a1      = (float*)ws;  ws += (size_t)NOUT_*KK_*4;
    float* a2      = (float*)ws;  ws += (size_t)NOUT_*KK_*4;
    float* scbi1   = (float*)ws;  ws += 256*4;
    float* scbi2   = (float*)ws;  ws += 256*4;
    float* stats   = (float*)ws;  ws += 640*4;   // sum1, sq1, sum2, sq2, fzero
    float* pbuf    = (float*)ws;  ws += (size_t)1024*256*4;  // 1MB partials
    _Float16* Wf1  = (_Float16*)ws; ws += (size_t)9*8192*2;
    _Float16* Wf2  = (_Float16*)ws; ws += (size_t)18*8192*2;
    _Float16* Ef   = (_Float16*)ws; ws += (size_t)8192*2;
    _Float16* xh   = (_Float16*)ws; ws += (size_t)NIN_*B_*CI_*2;   // 33.5MB
    _Float16* o1h  = (_Float16*)ws; ws += (size_t)NOUT_*B_*CO_*2;  // 16.8MB
    _Float16* o2h  = (_Float16*)ws; ws += (size_t)NOUT_*B_*CO_*2;  // 16.8MB

    float* sum1  = stats;       float* sq1 = stats + 128;
    float* sum2  = stats + 256; float* sq2 = stats + 384;
    float* fzero = stats + 512;

    zero_kernel<<<3, 256, 0, stream>>>(stats, 640);
    wnet_kernel<<<(NOUT_*KK_ + 255)/256, 256, 0, stream>>>(off1, off2, wn_w1, wn_b1, wn_w2, wn_b2, a1, a2);
    wpack_kernel<CI_><<<(9*8192 + 255)/256, 256, 0, stream>>>(W1, Wf1);
    wpack_kernel<CO_><<<(18*8192 + 255)/256, 256, 0, stream>>>(W2, Wf2);
    epack_kernel<<<32, 256, 0, stream>>>(exp_w, Ef);
    xtrans_kernel<<<dim3(NIN_/64, B_), 256, 0, stream>>>(x, xh);

    conv_mfma_kernel<CI_, false><<<NOUT_/16, 256, 0, stream>>>(xh, Wf1, nbr1, a1, nullptr, o1h, pbuf);
    bnreduce_kernel<<<32, 256, 0, stream>>>(pbuf, sum1);        // sum1||sq1
    bnparams_kernel<<<1, 128, 0, stream>>>(sum1, sq1, bn1_g, bn1_b, fzero, scbi1);

    conv_mfma_kernel<CO_, true><<<NOUT_/16, 256, 0, stream>>>(o1h, Wf2, nbr2, a2, scbi1, o2h, pbuf);
    bnreduce_kernel<<<32, 256, 0, stream>>>(pbuf, sum2);        // sum2||sq2
    bnparams_kernel<<<1, 128, 0, stream>>>(sum2, sq2, bn2_g, bn2_b, exp_b, scbi2);

    final_mfma_kernel<<<NOUT_/16, 256, 0, stream>>>(xh, o2h, pool_idx, Ef, scbi2, out);
}

// Round 9
// 156.669 us; speedup vs baseline: 1.1449x; 1.1449x over previous
//
#include <hip/hip_runtime.h>
#include <hip/hip_bf16.h>

// Problem constants
#define B_    4
#define CI_   64
#define CO_   128
#define NIN_  65536
#define NOUT_ 16384
#define KK_   9
#define PP_   4
#define HH_   32

typedef _Float16 f16x8 __attribute__((ext_vector_type(8)));
typedef _Float16 f16x4 __attribute__((ext_vector_type(4)));
typedef float    f32x4 __attribute__((ext_vector_type(4)));

// ---------------- fused prep kernel (wnet | wpack1 | wpack2 | epack) ----------------
// grid = 576 + 288 + 576 + 32 = 1472 blocks of 256.

__device__ __forceinline__ void wnet_body(int idx,
        const float* __restrict__ off1, const float* __restrict__ off2,
        const float* __restrict__ w1, const float* __restrict__ b1,
        const float* __restrict__ w2, const float* __restrict__ b2,
        float* __restrict__ a1, float* __restrict__ a2) {
    float x0 = off1[idx*2+0], x1 = off1[idx*2+1];
    float y0 = off2[idx*2+0], y1 = off2[idx*2+1];
    float bias2 = b2[0];
    float s1 = bias2, s2 = bias2;
    #pragma unroll
    for (int h = 0; h < HH_; ++h) {
        float wh0 = w1[h], wh1 = w1[HH_+h], bh = b1[h], vh = w2[h];
        s1 += fmaxf(x0*wh0 + x1*wh1 + bh, 0.f) * vh;
        s2 += fmaxf(y0*wh0 + y1*wh1 + bh, 0.f) * vh;
    }
    a1[idx] = s1;
    a2[idx] = s2;
}

// Pack W into per-lane MFMA A-fragment order (fp16).
// Wf element f = (((s*2+kap)*8 + ot)*64 + l)*8 + j holds
//   A[o = ot*16 + (l&15)][kel = kap*32 + ((l>>4)&3)*8 + j] of 64-ch slab s.
template<int CIN>
__device__ __forceinline__ void wpack_body(int f, const float* __restrict__ W,
                                           _Float16* __restrict__ Wf) {
    int j   = f & 7;
    int l   = (f >> 3) & 63;
    int ot  = (f >> 9) & 7;
    int kap = (f >> 12) & 1;
    int s   = f >> 13;
    int o   = ot*16 + (l & 15);
    int kel = kap*32 + ((l >> 4) & 3)*8 + j;
    int k, i;
    if (CIN == 64) { k = s; i = kel; }
    else           { k = s >> 1; i = ((s & 1) << 6) + kel; }
    Wf[f] = (_Float16)W[((size_t)o*CIN + i)*KK_ + k];
}

__global__ __launch_bounds__(256) void prep_kernel(
        const float* __restrict__ off1, const float* __restrict__ off2,
        const float* __restrict__ wn_w1, const float* __restrict__ wn_b1,
        const float* __restrict__ wn_w2, const float* __restrict__ wn_b2,
        const float* __restrict__ W1, const float* __restrict__ W2,
        const float* __restrict__ exp_w,
        float* __restrict__ a1, float* __restrict__ a2,
        _Float16* __restrict__ Wf1, _Float16* __restrict__ Wf2,
        _Float16* __restrict__ Ef) {
    const int blk = blockIdx.x;
    const int t   = threadIdx.x;
    if (blk < 576) {                       // wnet: 147456 elements
        wnet_body(blk*256 + t, off1, off2, wn_w1, wn_b1, wn_w2, wn_b2, a1, a2);
    } else if (blk < 576 + 288) {          // wpack1: 73728 elements
        wpack_body<CI_>((blk - 576)*256 + t, W1, Wf1);
    } else if (blk < 576 + 288 + 576) {    // wpack2: 147456 elements
        wpack_body<CO_>((blk - 864)*256 + t, W2, Wf2);
    } else {                               // epack: 8192 elements
        int f = (blk - 1440)*256 + t;
        int j   = f & 7;
        int l   = (f >> 3) & 63;
        int ot  = (f >> 9) & 7;
        int kap = (f >> 12) & 1;
        int o   = ot*16 + (l & 15);
        int i   = kap*32 + ((l >> 4) & 3)*8 + j;
        Ef[f] = (_Float16)exp_w[o*64 + i];
    }
}

// xT[p][b][i] (fp16) = x[b][i][p] (f32)
__global__ void xtrans_kernel(const float* __restrict__ x, _Float16* __restrict__ xT) {
    __shared__ float tile[64][65];
    int p0 = blockIdx.x * 64;
    int b  = blockIdx.y;
    int t  = threadIdx.x;
    #pragma unroll
    for (int r = 0; r < 16; ++r) {
        int f = r*256 + t;
        int i = f >> 6, pp = f & 63;
        tile[i][pp] = x[((size_t)(b*CI_ + i))*NIN_ + p0 + pp];
    }
    __syncthreads();
    #pragma unroll
    for (int r = 0; r < 2; ++r) {    // vectorized f16x8 stores
        int f  = r*256 + t;          // f in [0,512)
        int pp = f >> 3;
        int i0 = (f & 7) * 8;
        f16x8 v;
        #pragma unroll
        for (int e = 0; e < 8; ++e) v[e] = (_Float16)tile[i0+e][pp];
        *(f16x8*)(xT + ((size_t)(p0+pp)*B_ + b)*CI_ + i0) = v;
    }
}

// single-block stat reduce + BN params: sums pbuf[512][256] (coalesced), then
// scbi = {scale, bias(+eb)}.  No atomics, no zero-init dependency.
__global__ __launch_bounds__(256) void bnstats_kernel(const float* __restrict__ pbuf,
                                                      const float* __restrict__ g,
                                                      const float* __restrict__ bb,
                                                      const float* __restrict__ eb,
                                                      float* __restrict__ scbi) {
    const int t = threadIdx.x;
    float s = 0.f;
    #pragma unroll 8
    for (int b = 0; b < 512; ++b)
        s += pbuf[(size_t)b*256 + t];
    __shared__ float sm[256];
    sm[t] = s;
    __syncthreads();
    if (t < 128) {
        const float inv_n = 1.f / (B_ * NOUT_);
        float mean = sm[t] * inv_n;
        float var  = sm[128 + t] * inv_n - mean*mean;
        float sc   = g[t] * rsqrtf(var + 1e-5f);
        scbi[t]       = sc;
        scbi[128 + t] = bb[t] - mean*sc + (eb ? eb[t] : 0.f);
    }
}

// in-place BN+ReLU on t[65536][128] fp16
__global__ __launch_bounds__(256) void bnrelu_kernel(_Float16* __restrict__ t,
                                                     const float* __restrict__ scbi) {
    __shared__ float ssc[128], sbi[128];
    if (threadIdx.x < 128) {
        ssc[threadIdx.x] = scbi[threadIdx.x];
        sbi[threadIdx.x] = scbi[128 + threadIdx.x];
    }
    __syncthreads();
    size_t idx = ((size_t)blockIdx.x*256 + threadIdx.x) * 8;
    int o0 = (int)(idx & 127);
    f16x8 v = *(f16x8*)(t + idx);
    #pragma unroll
    for (int e = 0; e < 8; ++e) {
        float f = (float)v[e] * ssc[o0+e] + sbi[o0+e];
        v[e] = (_Float16)fmaxf(f, 0.f);
    }
    *(f16x8*)(t + idx) = v;
}

// ---------------- MFMA conv (implicit GEMM, gather-staged) — R5-validated ----------------
// out[n][o] = sum_{k,i} W[o,i,k] * a[m,k] * in[nbr[m,k]*B+b][i],  n = mi*4+b.
// Block: 128 o x 128 n (32 m), 4 waves (2x2), each wave 64x64 via 4x4 16x16x32 frags.
// Conv2 is L2-fill-bound (~60MB FETCH @ ~1.3TB/s across R5/R6/R7 structures) — this
// is the best-measured structure (46 µs conv2, 21-26 µs conv1).
template<int CIN, int NSLAB>
__global__ __launch_bounds__(256, 2) void conv_mfma_kernel(
    const _Float16* __restrict__ in,    // [Npts*B][CIN]
    const _Float16* __restrict__ Wf,    // frag-packed fp16
    const int*      __restrict__ nbr,   // [NOUT][K]
    const float*    __restrict__ amk,   // [NOUT][K]
    _Float16*       __restrict__ outh,  // [NOUT*B][128] raw (pre-BN)
    float*          __restrict__ pbuf)  // [512][256] partial sums/sumsq
{
    __shared__ _Float16 Gs[128*64];     // XOR-swizzled: chunk ^= row&7
    const int t    = threadIdx.x;
    const int lane = t & 63;
    const int wid  = t >> 6;
    const int wr   = wid >> 1, wc = wid & 1;
    const int m0   = blockIdx.x * 32;
    const int l15 = lane & 15, l4 = lane >> 4, l7 = lane & 7;
    // staging assignment: thread -> (row n, half h)
    const int srow = t >> 1;
    const int sh   = t & 1;
    const int sm   = m0 + (srow >> 2);
    const int sb   = srow & 3;

    f32x4 acc[4][4];
    #pragma unroll
    for (int c = 0; c < 4; ++c)
        #pragma unroll
        for (int j = 0; j < 4; ++j)
            acc[c][j] = (f32x4){0.f, 0.f, 0.f, 0.f};

    for (int s = 0; s < NSLAB; ++s) {
        const int k    = (CIN == 64) ? s : (s >> 1);
        const int ioff = (CIN == 64) ? 0 : ((s & 1) << 6);
        // A fragments straight from global (frag-packed, coalesced, L2-hot)
        f16x8 aF[2][4];
        #pragma unroll
        for (int kap = 0; kap < 2; ++kap)
            #pragma unroll
            for (int c = 0; c < 4; ++c)
                aF[kap][c] = *(const f16x8*)(Wf +
                    ((size_t)((s*2 + kap)*8 + (wr*4 + c))*64 + lane)*8);
        // gather + scale
        const int   p  = nbr[sm*KK_ + k];
        const float av = amk[sm*KK_ + k];
        const _Float16 hs = (_Float16)av;
        const _Float16* src = in + ((size_t)p*B_ + sb)*CIN + ioff + sh*32;
        f16x8 g[4];
        #pragma unroll
        for (int q = 0; q < 4; ++q) g[q] = *(const f16x8*)(src + q*8);
        __syncthreads();   // previous slab's compute done before overwrite
        #pragma unroll
        for (int q = 0; q < 4; ++q) {
            f16x8 v = g[q];
            #pragma unroll
            for (int e = 0; e < 8; ++e) v[e] = v[e] * hs;
            const int c4 = sh*4 + q;
            *(f16x8*)(Gs + srow*64 + ((c4 ^ (srow & 7)) << 3)) = v;
        }
        __syncthreads();
        // compute
        #pragma unroll
        for (int kap = 0; kap < 2; ++kap) {
            f16x8 bF[4];
            #pragma unroll
            for (int jt = 0; jt < 4; ++jt) {
                const int row = wc*64 + jt*16 + l15;
                const int ch  = (kap*4 + l4) ^ l7;   // row&7 == l7 (row base mult of 16)
                bF[jt] = *(const f16x8*)(Gs + row*64 + (ch << 3));
            }
            #pragma unroll
            for (int c = 0; c < 4; ++c)
                #pragma unroll
                for (int jt = 0; jt < 4; ++jt)
                    acc[c][jt] = __builtin_amdgcn_mfma_f32_16x16x32_f16(
                        aF[kap][c], bF[jt], acc[c][jt], 0, 0, 0);
        }
    }
    // ---- in-register BN statistics -> per-block partial (deterministic) ----
    // element at (o = wr*64 + c*16 + l4*4 + r,  n = wc*64 + jt*16 + l15)
    __syncthreads();                 // all waves done reading Gs
    float* red = (float*)Gs;         // [wc][stat][128 o] = 512 floats
    #pragma unroll
    for (int c = 0; c < 4; ++c) {
        #pragma unroll
        for (int r = 0; r < 4; ++r) {
            float s = acc[c][0][r] + acc[c][1][r] + acc[c][2][r] + acc[c][3][r];
            float q = acc[c][0][r]*acc[c][0][r] + acc[c][1][r]*acc[c][1][r]
                    + acc[c][2][r]*acc[c][2][r] + acc[c][3][r]*acc[c][3][r];
            #pragma unroll
            for (int msk = 1; msk <= 8; msk <<= 1) {
                s += __shfl_xor(s, msk);
                q += __shfl_xor(q, msk);
            }
            if (l15 == 0) {
                const int o = wr*64 + c*16 + l4*4 + r;
                red[wc*256 + o]       = s;
                red[wc*256 + 128 + o] = q;
            }
        }
    }
    __syncthreads();
    pbuf[(size_t)blockIdx.x*256 + t] = red[t] + red[256 + t];  // coalesced 1KB
    // epilogue: direct fp16 store (D: col=lane&15, row=(lane>>4)*4+reg)
    #pragma unroll
    for (int c = 0; c < 4; ++c) {
        const int o = wr*64 + c*16 + l4*4;
        #pragma unroll
        for (int jt = 0; jt < 4; ++jt) {
            const int n = wc*64 + jt*16 + l15;
            f16x4 h;
            #pragma unroll
            for (int r = 0; r < 4; ++r) h[r] = (_Float16)acc[c][jt][r];
            *(f16x4*)(outh + ((size_t)(m0*B_) + n)*CO_ + o) = h;
        }
    }
}

// ---------------- final: MFMA identity GEMM + BN2 + add + relu ----------------
__global__ __launch_bounds__(256, 4) void final_mfma_kernel(
    const _Float16* __restrict__ xh,      // [NIN*B][64]
    const _Float16* __restrict__ out2T,   // [NOUT*B][128] raw (pre-BN)
    const int*      __restrict__ pool_idx,// [NOUT][4]
    const _Float16* __restrict__ Ef,      // frag-packed exp_w
    const float*    __restrict__ scbi2,   // sc[128] | (bi+exp_b)[128]
    float*          __restrict__ out)     // [B][128][NOUT]
{
    __shared__ _Float16 Gs[64*64];        // XOR-swizzled pooled tile
    const int t    = threadIdx.x;
    const int lane = t & 63;
    const int wid  = t >> 6;
    const int wr   = wid >> 1, wc = wid & 1;
    const int m0   = blockIdx.x * 16;
    const int l15 = lane & 15, l4 = lane >> 4, l7 = lane & 7;

    // ---- staging: pooled rows, vectorized f16x8 gather ----
    {
        const int srow = t >> 2;          // n = b*16 + mi
        const int sq   = t & 3;           // 16-element quarter
        const int m    = m0 + (srow & 15);
        const int b    = srow >> 4;
        const int4 pidx = *(const int4*)(pool_idx + m*4);
        const _Float16* r0 = xh + ((size_t)pidx.x*B_ + b)*CI_ + sq*16;
        const _Float16* r1 = xh + ((size_t)pidx.y*B_ + b)*CI_ + sq*16;
        const _Float16* r2 = xh + ((size_t)pidx.z*B_ + b)*CI_ + sq*16;
        const _Float16* r3 = xh + ((size_t)pidx.w*B_ + b)*CI_ + sq*16;
        #pragma unroll
        for (int q = 0; q < 2; ++q) {
            f16x8 v  = *(const f16x8*)(r0 + q*8);
            f16x8 v1 = *(const f16x8*)(r1 + q*8);
            f16x8 v2 = *(const f16x8*)(r2 + q*8);
            f16x8 v3 = *(const f16x8*)(r3 + q*8);
            v = v + v1 + v2 + v3;
            #pragma unroll
            for (int e = 0; e < 8; ++e) v[e] = v[e] * (_Float16)0.25f;
            const int c4 = sq*2 + q;
            *(f16x8*)(Gs + srow*64 + ((c4 ^ (srow & 7)) << 3)) = v;
        }
    }
    __syncthreads();

    // ---- MFMA: identity = exp_w @ pooled ----
    f32x4 acc[4][2];
    #pragma unroll
    for (int c = 0; c < 4; ++c)
        #pragma unroll
        for (int j = 0; j < 2; ++j)
            acc[c][j] = (f32x4){0.f, 0.f, 0.f, 0.f};
    #pragma unroll
    for (int kap = 0; kap < 2; ++kap) {
        f16x8 aF[4], bF[2];
        #pragma unroll
        for (int c = 0; c < 4; ++c)
            aF[c] = *(const f16x8*)(Ef + ((size_t)((kap*8 + wr*4 + c)*64 + lane))*8);
        #pragma unroll
        for (int jt = 0; jt < 2; ++jt) {
            const int row = wc*32 + jt*16 + l15;
            const int ch  = (kap*4 + l4) ^ l7;
            bF[jt] = *(const f16x8*)(Gs + row*64 + (ch << 3));
        }
        #pragma unroll
        for (int c = 0; c < 4; ++c)
            #pragma unroll
            for (int jt = 0; jt < 2; ++jt)
                acc[c][jt] = __builtin_amdgcn_mfma_f32_16x16x32_f16(
                    aF[c], bF[jt], acc[c][jt], 0, 0, 0);
    }

    // ---- epilogue: BN2(out2T) + identity + relu -> out[b][o][m] ----
    const int m = m0 + l15;
    #pragma unroll
    for (int c = 0; c < 4; ++c) {
        const int o = wr*64 + c*16 + l4*4;
        const float4 sc4 = *(const float4*)(scbi2 + o);
        const float4 bi4 = *(const float4*)(scbi2 + 128 + o);
        #pragma unroll
        for (int jt = 0; jt < 2; ++jt) {
            const int b = wc*2 + jt;     // n = wc*32+jt*16+l15 -> b = n>>4
            const f16x4 v2 = *(const f16x4*)(out2T + ((size_t)(m*B_ + b))*CO_ + o);
            float res0 = fmaxf(acc[c][jt][0] + (float)v2[0]*sc4.x + bi4.x, 0.f);
            float res1 = fmaxf(acc[c][jt][1] + (float)v2[1]*sc4.y + bi4.y, 0.f);
            float res2 = fmaxf(acc[c][jt][2] + (float)v2[2]*sc4.z + bi4.z, 0.f);
            float res3 = fmaxf(acc[c][jt][3] + (float)v2[3]*sc4.w + bi4.w, 0.f);
            out[((size_t)(b*CO_ + o + 0))*NOUT_ + m] = res0;
            out[((size_t)(b*CO_ + o + 1))*NOUT_ + m] = res1;
            out[((size_t)(b*CO_ + o + 2))*NOUT_ + m] = res2;
            out[((size_t)(b*CO_ + o + 3))*NOUT_ + m] = res3;
        }
    }
}

// ---------------- launch ----------------
extern "C" void kernel_launch(void* const* d_in, const int* in_sizes, int n_in,
                              void* d_out, int out_size, void* d_ws, size_t ws_size,
                              hipStream_t stream) {
    const float* x        = (const float*)d_in[0];
    const float* off1     = (const float*)d_in[1];
    const float* off2     = (const float*)d_in[2];
    const int*   nbr1     = (const int*)  d_in[3];
    const int*   nbr2     = (const int*)  d_in[4];
    const int*   pool_idx = (const int*)  d_in[5];
    const float* wn_w1    = (const float*)d_in[6];
    const float* wn_b1    = (const float*)d_in[7];
    const float* wn_w2    = (const float*)d_in[8];
    const float* wn_b2    = (const float*)d_in[9];
    const float* W1       = (const float*)d_in[10];
    const float* W2       = (const float*)d_in[11];
    const float* bn1_g    = (const float*)d_in[12];
    const float* bn1_b    = (const float*)d_in[13];
    const float* bn2_g    = (const float*)d_in[14];
    const float* bn2_b    = (const float*)d_in[15];
    const float* exp_w    = (const float*)d_in[16];
    const float* exp_b    = (const float*)d_in[17];
    float* out = (float*)d_out;

    // workspace carve (~68.5 MB)
    char* ws = (char*)d_ws;
    float* a1      = (float*)ws;  ws += (size_t)NOUT_*KK_*4;
    float* a2      = (float*)ws;  ws += (size_t)NOUT_*KK_*4;
    float* scbi1   = (float*)ws;  ws += 256*4;
    float* scbi2   = (float*)ws;  ws += 256*4;
    float* pbuf    = (float*)ws;  ws += (size_t)512*256*4;   // 512KB partials
    _Float16* Wf1  = (_Float16*)ws; ws += (size_t)9*8192*2;
    _Float16* Wf2  = (_Float16*)ws; ws += (size_t)18*8192*2;
    _Float16* Ef   = (_Float16*)ws; ws += (size_t)8192*2;
    _Float16* xh   = (_Float16*)ws; ws += (size_t)NIN_*B_*CI_*2;   // 33.5MB
    _Float16* o1h  = (_Float16*)ws; ws += (size_t)NOUT_*B_*CO_*2;  // 16.8MB
    _Float16* o2h  = (_Float16*)ws; ws += (size_t)NOUT_*B_*CO_*2;  // 16.8MB

    prep_kernel<<<1472, 256, 0, stream>>>(off1, off2, wn_w1, wn_b1, wn_w2, wn_b2,
                                          W1, W2, exp_w, a1, a2, Wf1, Wf2, Ef);
    xtrans_kernel<<<dim3(NIN_/64, B_), 256, 0, stream>>>(x, xh);

    conv_mfma_kernel<CI_, 9><<<NOUT_/32, 256, 0, stream>>>(xh, Wf1, nbr1, a1, o1h, pbuf);
    bnstats_kernel<<<1, 256, 0, stream>>>(pbuf, bn1_g, bn1_b, nullptr, scbi1);
    bnrelu_kernel<<<4096, 256, 0, stream>>>(o1h, scbi1);

    conv_mfma_kernel<CO_, 18><<<NOUT_/32, 256, 0, stream>>>(o1h, Wf2, nbr2, a2, o2h, pbuf);
    bnstats_kernel<<<1, 256, 0, stream>>>(pbuf, bn2_g, bn2_b, exp_b, scbi2);

    final_mfma_kernel<<<NOUT_/16, 256, 0, stream>>>(xh, o2h, pool_idx, Ef, scbi2, out);
}

// Round 10
// 115.867 us; speedup vs baseline: 1.5481x; 1.3521x over previous
//
#include <hip/hip_runtime.h>
#include <hip/hip_bf16.h>

// Problem constants
#define B_    4
#define CI_   64
#define CO_   128
#define NIN_  65536
#define NOUT_ 16384
#define KK_   9
#define PP_   4
#define HH_   32

typedef _Float16 f16x8 __attribute__((ext_vector_type(8)));
typedef _Float16 f16x4 __attribute__((ext_vector_type(4)));
typedef float    f32x4 __attribute__((ext_vector_type(4)));

// ---------------- fused prep kernel (wnet | wpack1 | wpack2 | epack | xtrans) ----------------
// grid = 576 + 288 + 576 + 32 + 4096 = 5568 blocks of 256.

__device__ __forceinline__ void wnet_body(int idx,
        const float* __restrict__ off1, const float* __restrict__ off2,
        const float* __restrict__ w1, const float* __restrict__ b1,
        const float* __restrict__ w2, const float* __restrict__ b2,
        float* __restrict__ a1, float* __restrict__ a2) {
    float x0 = off1[idx*2+0], x1 = off1[idx*2+1];
    float y0 = off2[idx*2+0], y1 = off2[idx*2+1];
    float bias2 = b2[0];
    float s1 = bias2, s2 = bias2;
    #pragma unroll
    for (int h = 0; h < HH_; ++h) {
        float wh0 = w1[h], wh1 = w1[HH_+h], bh = b1[h], vh = w2[h];
        s1 += fmaxf(x0*wh0 + x1*wh1 + bh, 0.f) * vh;
        s2 += fmaxf(y0*wh0 + y1*wh1 + bh, 0.f) * vh;
    }
    a1[idx] = s1;
    a2[idx] = s2;
}

// Pack W into per-lane MFMA A-fragment order (fp16).
// Wf element f = (((s*2+kap)*8 + ot)*64 + l)*8 + j holds
//   A[o = ot*16 + (l&15)][kel = kap*32 + ((l>>4)&3)*8 + j] of 64-ch slab s.
template<int CIN>
__device__ __forceinline__ void wpack_body(int f, const float* __restrict__ W,
                                           _Float16* __restrict__ Wf) {
    int j   = f & 7;
    int l   = (f >> 3) & 63;
    int ot  = (f >> 9) & 7;
    int kap = (f >> 12) & 1;
    int s   = f >> 13;
    int o   = ot*16 + (l & 15);
    int kel = kap*32 + ((l >> 4) & 3)*8 + j;
    int k, i;
    if (CIN == 64) { k = s; i = kel; }
    else           { k = s >> 1; i = ((s & 1) << 6) + kel; }
    Wf[f] = (_Float16)W[((size_t)o*CIN + i)*KK_ + k];
}

__global__ __launch_bounds__(256) void prep_kernel(
        const float* __restrict__ off1, const float* __restrict__ off2,
        const float* __restrict__ wn_w1, const float* __restrict__ wn_b1,
        const float* __restrict__ wn_w2, const float* __restrict__ wn_b2,
        const float* __restrict__ W1, const float* __restrict__ W2,
        const float* __restrict__ exp_w, const float* __restrict__ x,
        float* __restrict__ a1, float* __restrict__ a2,
        _Float16* __restrict__ Wf1, _Float16* __restrict__ Wf2,
        _Float16* __restrict__ Ef, _Float16* __restrict__ xT) {
    __shared__ float tile[64][65];
    const int blk = blockIdx.x;
    const int t   = threadIdx.x;
    if (blk < 576) {                       // wnet: 147456 elements
        wnet_body(blk*256 + t, off1, off2, wn_w1, wn_b1, wn_w2, wn_b2, a1, a2);
    } else if (blk < 576 + 288) {          // wpack1: 73728 elements
        wpack_body<CI_>((blk - 576)*256 + t, W1, Wf1);
    } else if (blk < 576 + 288 + 576) {    // wpack2: 147456 elements
        wpack_body<CO_>((blk - 864)*256 + t, W2, Wf2);
    } else if (blk < 1472) {               // epack: 8192 elements
        int f = (blk - 1440)*256 + t;
        int j   = f & 7;
        int l   = (f >> 3) & 63;
        int ot  = (f >> 9) & 7;
        int kap = (f >> 12) & 1;
        int o   = ot*16 + (l & 15);
        int i   = kap*32 + ((l >> 4) & 3)*8 + j;
        Ef[f] = (_Float16)exp_w[o*64 + i];
    } else {                               // xtrans: xT[p][b][i] = x[b][i][p]
        const int bk = blk - 1472;         // 4096 blocks
        const int p0 = (bk >> 2) * 64;
        const int b  = bk & 3;
        #pragma unroll
        for (int r = 0; r < 16; ++r) {
            int f = r*256 + t;
            int i = f >> 6, pp = f & 63;
            tile[i][pp] = x[((size_t)(b*CI_ + i))*NIN_ + p0 + pp];
        }
        __syncthreads();
        #pragma unroll
        for (int r = 0; r < 2; ++r) {      // vectorized f16x8 stores
            int f  = r*256 + t;            // f in [0,512)
            int pp = f >> 3;
            int i0 = (f & 7) * 8;
            f16x8 v;
            #pragma unroll
            for (int e = 0; e < 8; ++e) v[e] = (_Float16)tile[i0+e][pp];
            *(f16x8*)(xT + ((size_t)(p0+pp)*B_ + b)*CI_ + i0) = v;
        }
    }
}

// stage-1 stat reduce: 32 blocks x 16 source rows -> pbuf2[32][256] (no atomics)
__global__ __launch_bounds__(256) void bnreduce_kernel(const float* __restrict__ pbuf,
                                                       float* __restrict__ pbuf2) {
    const int t = threadIdx.x;
    float s = 0.f;
    const int base = blockIdx.x * 16;
    #pragma unroll
    for (int b = 0; b < 16; ++b)
        s += pbuf[(size_t)(base + b)*256 + t];
    pbuf2[blockIdx.x*256 + t] = s;
}

// stage-2: sum 32 partial rows, compute scale / (bias + extra_bias)
__global__ __launch_bounds__(256) void bnparams_kernel(const float* __restrict__ pbuf2,
                                                       const float* __restrict__ g,
                                                       const float* __restrict__ bb,
                                                       const float* __restrict__ eb,
                                                       float* __restrict__ scbi) {
    const int t = threadIdx.x;
    float s = 0.f;
    #pragma unroll
    for (int b = 0; b < 32; ++b)
        s += pbuf2[b*256 + t];
    __shared__ float sm[256];
    sm[t] = s;
    __syncthreads();
    if (t < 128) {
        const float inv_n = 1.f / (B_ * NOUT_);
        float mean = sm[t] * inv_n;
        float var  = sm[128 + t] * inv_n - mean*mean;
        float sc   = g[t] * rsqrtf(var + 1e-5f);
        scbi[t]       = sc;
        scbi[128 + t] = bb[t] - mean*sc + (eb ? eb[t] : 0.f);
    }
}

// in-place BN+ReLU on t[65536][128] fp16
__global__ __launch_bounds__(256) void bnrelu_kernel(_Float16* __restrict__ t,
                                                     const float* __restrict__ scbi) {
    __shared__ float ssc[128], sbi[128];
    if (threadIdx.x < 128) {
        ssc[threadIdx.x] = scbi[threadIdx.x];
        sbi[threadIdx.x] = scbi[128 + threadIdx.x];
    }
    __syncthreads();
    size_t idx = ((size_t)blockIdx.x*256 + threadIdx.x) * 8;
    int o0 = (int)(idx & 127);
    f16x8 v = *(f16x8*)(t + idx);
    #pragma unroll
    for (int e = 0; e < 8; ++e) {
        float f = (float)v[e] * ssc[o0+e] + sbi[o0+e];
        v[e] = (_Float16)fmaxf(f, 0.f);
    }
    *(f16x8*)(t + idx) = v;
}

// ---------------- MFMA conv (implicit GEMM, gather-staged) — R5-validated ----------------
// out[n][o] = sum_{k,i} W[o,i,k] * a[m,k] * in[nbr[m,k]*B+b][i],  n = mi*4+b.
// Block: 128 o x 128 n (32 m), 4 waves (2x2), each wave 64x64 via 4x4 16x16x32 frags.
// Conv2 is memory-system-bound on the random gather (R5/R6/R7: three structures,
// FETCH~60MB, 46-63 µs) — this is the best-measured structure.
template<int CIN, int NSLAB>
__global__ __launch_bounds__(256, 2) void conv_mfma_kernel(
    const _Float16* __restrict__ in,    // [Npts*B][CIN]
    const _Float16* __restrict__ Wf,    // frag-packed fp16
    const int*      __restrict__ nbr,   // [NOUT][K]
    const float*    __restrict__ amk,   // [NOUT][K]
    _Float16*       __restrict__ outh,  // [NOUT*B][128] raw (pre-BN)
    float*          __restrict__ pbuf)  // [512][256] partial sums/sumsq
{
    __shared__ _Float16 Gs[128*64];     // XOR-swizzled: chunk ^= row&7
    const int t    = threadIdx.x;
    const int lane = t & 63;
    const int wid  = t >> 6;
    const int wr   = wid >> 1, wc = wid & 1;
    const int m0   = blockIdx.x * 32;
    const int l15 = lane & 15, l4 = lane >> 4, l7 = lane & 7;
    // staging assignment: thread -> (row n, half h)
    const int srow = t >> 1;
    const int sh   = t & 1;
    const int sm   = m0 + (srow >> 2);
    const int sb   = srow & 3;

    f32x4 acc[4][4];
    #pragma unroll
    for (int c = 0; c < 4; ++c)
        #pragma unroll
        for (int j = 0; j < 4; ++j)
            acc[c][j] = (f32x4){0.f, 0.f, 0.f, 0.f};

    for (int s = 0; s < NSLAB; ++s) {
        const int k    = (CIN == 64) ? s : (s >> 1);
        const int ioff = (CIN == 64) ? 0 : ((s & 1) << 6);
        // A fragments straight from global (frag-packed, coalesced, L2-hot)
        f16x8 aF[2][4];
        #pragma unroll
        for (int kap = 0; kap < 2; ++kap)
            #pragma unroll
            for (int c = 0; c < 4; ++c)
                aF[kap][c] = *(const f16x8*)(Wf +
                    ((size_t)((s*2 + kap)*8 + (wr*4 + c))*64 + lane)*8);
        // gather + scale
        const int   p  = nbr[sm*KK_ + k];
        const float av = amk[sm*KK_ + k];
        const _Float16 hs = (_Float16)av;
        const _Float16* src = in + ((size_t)p*B_ + sb)*CIN + ioff + sh*32;
        f16x8 g[4];
        #pragma unroll
        for (int q = 0; q < 4; ++q) g[q] = *(const f16x8*)(src + q*8);
        __syncthreads();   // previous slab's compute done before overwrite
        #pragma unroll
        for (int q = 0; q < 4; ++q) {
            f16x8 v = g[q];
            #pragma unroll
            for (int e = 0; e < 8; ++e) v[e] = v[e] * hs;
            const int c4 = sh*4 + q;
            *(f16x8*)(Gs + srow*64 + ((c4 ^ (srow & 7)) << 3)) = v;
        }
        __syncthreads();
        // compute
        #pragma unroll
        for (int kap = 0; kap < 2; ++kap) {
            f16x8 bF[4];
            #pragma unroll
            for (int jt = 0; jt < 4; ++jt) {
                const int row = wc*64 + jt*16 + l15;
                const int ch  = (kap*4 + l4) ^ l7;   // row&7 == l7 (row base mult of 16)
                bF[jt] = *(const f16x8*)(Gs + row*64 + (ch << 3));
            }
            #pragma unroll
            for (int c = 0; c < 4; ++c)
                #pragma unroll
                for (int jt = 0; jt < 4; ++jt)
                    acc[c][jt] = __builtin_amdgcn_mfma_f32_16x16x32_f16(
                        aF[kap][c], bF[jt], acc[c][jt], 0, 0, 0);
        }
    }
    // ---- in-register BN statistics -> per-block partial (deterministic) ----
    // element at (o = wr*64 + c*16 + l4*4 + r,  n = wc*64 + jt*16 + l15)
    __syncthreads();                 // all waves done reading Gs
    float* red = (float*)Gs;         // [wc][stat][128 o] = 512 floats
    #pragma unroll
    for (int c = 0; c < 4; ++c) {
        #pragma unroll
        for (int r = 0; r < 4; ++r) {
            float s = acc[c][0][r] + acc[c][1][r] + acc[c][2][r] + acc[c][3][r];
            float q = acc[c][0][r]*acc[c][0][r] + acc[c][1][r]*acc[c][1][r]
                    + acc[c][2][r]*acc[c][2][r] + acc[c][3][r]*acc[c][3][r];
            #pragma unroll
            for (int msk = 1; msk <= 8; msk <<= 1) {
                s += __shfl_xor(s, msk);
                q += __shfl_xor(q, msk);
            }
            if (l15 == 0) {
                const int o = wr*64 + c*16 + l4*4 + r;
                red[wc*256 + o]       = s;
                red[wc*256 + 128 + o] = q;
            }
        }
    }
    __syncthreads();
    pbuf[(size_t)blockIdx.x*256 + t] = red[t] + red[256 + t];  // coalesced 1KB
    // epilogue: direct fp16 store (D: col=lane&15, row=(lane>>4)*4+reg)
    #pragma unroll
    for (int c = 0; c < 4; ++c) {
        const int o = wr*64 + c*16 + l4*4;
        #pragma unroll
        for (int jt = 0; jt < 4; ++jt) {
            const int n = wc*64 + jt*16 + l15;
            f16x4 h;
            #pragma unroll
            for (int r = 0; r < 4; ++r) h[r] = (_Float16)acc[c][jt][r];
            *(f16x4*)(outh + ((size_t)(m0*B_) + n)*CO_ + o) = h;
        }
    }
}

// ---------------- final: MFMA identity GEMM + BN2 + add + relu ----------------
__global__ __launch_bounds__(256, 4) void final_mfma_kernel(
    const _Float16* __restrict__ xh,      // [NIN*B][64]
    const _Float16* __restrict__ out2T,   // [NOUT*B][128] raw (pre-BN)
    const int*      __restrict__ pool_idx,// [NOUT][4]
    const _Float16* __restrict__ Ef,      // frag-packed exp_w
    const float*    __restrict__ scbi2,   // sc[128] | (bi+exp_b)[128]
    float*          __restrict__ out)     // [B][128][NOUT]
{
    __shared__ _Float16 Gs[64*64];        // XOR-swizzled pooled tile
    const int t    = threadIdx.x;
    const int lane = t & 63;
    const int wid  = t >> 6;
    const int wr   = wid >> 1, wc = wid & 1;
    const int m0   = blockIdx.x * 16;
    const int l15 = lane & 15, l4 = lane >> 4, l7 = lane & 7;

    // ---- staging: pooled rows, vectorized f16x8 gather ----
    {
        const int srow = t >> 2;          // n = b*16 + mi
        const int sq   = t & 3;           // 16-element quarter
        const int m    = m0 + (srow & 15);
        const int b    = srow >> 4;
        const int4 pidx = *(const int4*)(pool_idx + m*4);
        const _Float16* r0 = xh + ((size_t)pidx.x*B_ + b)*CI_ + sq*16;
        const _Float16* r1 = xh + ((size_t)pidx.y*B_ + b)*CI_ + sq*16;
        const _Float16* r2 = xh + ((size_t)pidx.z*B_ + b)*CI_ + sq*16;
        const _Float16* r3 = xh + ((size_t)pidx.w*B_ + b)*CI_ + sq*16;
        #pragma unroll
        for (int q = 0; q < 2; ++q) {
            f16x8 v  = *(const f16x8*)(r0 + q*8);
            f16x8 v1 = *(const f16x8*)(r1 + q*8);
            f16x8 v2 = *(const f16x8*)(r2 + q*8);
            f16x8 v3 = *(const f16x8*)(r3 + q*8);
            v = v + v1 + v2 + v3;
            #pragma unroll
            for (int e = 0; e < 8; ++e) v[e] = v[e] * (_Float16)0.25f;
            const int c4 = sq*2 + q;
            *(f16x8*)(Gs + srow*64 + ((c4 ^ (srow & 7)) << 3)) = v;
        }
    }
    __syncthreads();

    // ---- MFMA: identity = exp_w @ pooled ----
    f32x4 acc[4][2];
    #pragma unroll
    for (int c = 0; c < 4; ++c)
        #pragma unroll
        for (int j = 0; j < 2; ++j)
            acc[c][j] = (f32x4){0.f, 0.f, 0.f, 0.f};
    #pragma unroll
    for (int kap = 0; kap < 2; ++kap) {
        f16x8 aF[4], bF[2];
        #pragma unroll
        for (int c = 0; c < 4; ++c)
            aF[c] = *(const f16x8*)(Ef + ((size_t)((kap*8 + wr*4 + c)*64 + lane))*8);
        #pragma unroll
        for (int jt = 0; jt < 2; ++jt) {
            const int row = wc*32 + jt*16 + l15;
            const int ch  = (kap*4 + l4) ^ l7;
            bF[jt] = *(const f16x8*)(Gs + row*64 + (ch << 3));
        }
        #pragma unroll
        for (int c = 0; c < 4; ++c)
            #pragma unroll
            for (int jt = 0; jt < 2; ++jt)
                acc[c][jt] = __builtin_amdgcn_mfma_f32_16x16x32_f16(
                    aF[c], bF[jt], acc[c][jt], 0, 0, 0);
    }

    // ---- epilogue: BN2(out2T) + identity + relu -> out[b][o][m] ----
    const int m = m0 + l15;
    #pragma unroll
    for (int c = 0; c < 4; ++c) {
        const int o = wr*64 + c*16 + l4*4;
        const float4 sc4 = *(const float4*)(scbi2 + o);
        const float4 bi4 = *(const float4*)(scbi2 + 128 + o);
        #pragma unroll
        for (int jt = 0; jt < 2; ++jt) {
            const int b = wc*2 + jt;     // n = wc*32+jt*16+l15 -> b = n>>4
            const f16x4 v2 = *(const f16x4*)(out2T + ((size_t)(m*B_ + b))*CO_ + o);
            float res0 = fmaxf(acc[c][jt][0] + (float)v2[0]*sc4.x + bi4.x, 0.f);
            float res1 = fmaxf(acc[c][jt][1] + (float)v2[1]*sc4.y + bi4.y, 0.f);
            float res2 = fmaxf(acc[c][jt][2] + (float)v2[2]*sc4.z + bi4.z, 0.f);
            float res3 = fmaxf(acc[c][jt][3] + (float)v2[3]*sc4.w + bi4.w, 0.f);
            out[((size_t)(b*CO_ + o + 0))*NOUT_ + m] = res0;
            out[((size_t)(b*CO_ + o + 1))*NOUT_ + m] = res1;
            out[((size_t)(b*CO_ + o + 2))*NOUT_ + m] = res2;
            out[((size_t)(b*CO_ + o + 3))*NOUT_ + m] = res3;
        }
    }
}

// ---------------- launch ----------------
extern "C" void kernel_launch(void* const* d_in, const int* in_sizes, int n_in,
                              void* d_out, int out_size, void* d_ws, size_t ws_size,
                              hipStream_t stream) {
    const float* x        = (const float*)d_in[0];
    const float* off1     = (const float*)d_in[1];
    const float* off2     = (const float*)d_in[2];
    const int*   nbr1     = (const int*)  d_in[3];
    const int*   nbr2     = (const int*)  d_in[4];
    const int*   pool_idx = (const int*)  d_in[5];
    const float* wn_w1    = (const float*)d_in[6];
    const float* wn_b1    = (const float*)d_in[7];
    const float* wn_w2    = (const float*)d_in[8];
    const float* wn_b2    = (const float*)d_in[9];
    const float* W1       = (const float*)d_in[10];
    const float* W2       = (const float*)d_in[11];
    const float* bn1_g    = (const float*)d_in[12];
    const float* bn1_b    = (const float*)d_in[13];
    const float* bn2_g    = (const float*)d_in[14];
    const float* bn2_b    = (const float*)d_in[15];
    const float* exp_w    = (const float*)d_in[16];
    const float* exp_b    = (const float*)d_in[17];
    float* out = (float*)d_out;

    // workspace carve (~68.5 MB)
    char* ws = (char*)d_ws;
    float* a1      = (float*)ws;  ws += (size_t)NOUT_*KK_*4;
    float* a2      = (float*)ws;  ws += (size_t)NOUT_*KK_*4;
    float* scbi1   = (float*)ws;  ws += 256*4;
    float* scbi2   = (float*)ws;  ws += 256*4;
    float* pbuf    = (float*)ws;  ws += (size_t)512*256*4;   // 512KB partials
    float* pbuf2   = (float*)ws;  ws += (size_t)32*256*4;    // 32KB stage-2
    _Float16* Wf1  = (_Float16*)ws; ws += (size_t)9*8192*2;
    _Float16* Wf2  = (_Float16*)ws; ws += (size_t)18*8192*2;
    _Float16* Ef   = (_Float16*)ws; ws += (size_t)8192*2;
    _Float16* xh   = (_Float16*)ws; ws += (size_t)NIN_*B_*CI_*2;   // 33.5MB
    _Float16* o1h  = (_Float16*)ws; ws += (size_t)NOUT_*B_*CO_*2;  // 16.8MB
    _Float16* o2h  = (_Float16*)ws; ws += (size_t)NOUT_*B_*CO_*2;  // 16.8MB

    prep_kernel<<<5568, 256, 0, stream>>>(off1, off2, wn_w1, wn_b1, wn_w2, wn_b2,
                                          W1, W2, exp_w, x, a1, a2, Wf1, Wf2, Ef, xh);

    conv_mfma_kernel<CI_, 9><<<NOUT_/32, 256, 0, stream>>>(xh, Wf1, nbr1, a1, o1h, pbuf);
    bnreduce_kernel<<<32, 256, 0, stream>>>(pbuf, pbuf2);
    bnparams_kernel<<<1, 256, 0, stream>>>(pbuf2, bn1_g, bn1_b, nullptr, scbi1);
    bnrelu_kernel<<<4096, 256, 0, stream>>>(o1h, scbi1);

    conv_mfma_kernel<CO_, 18><<<NOUT_/32, 256, 0, stream>>>(o1h, Wf2, nbr2, a2, o2h, pbuf);
    bnreduce_kernel<<<32, 256, 0, stream>>>(pbuf, pbuf2);
    bnparams_kernel<<<1, 256, 0, stream>>>(pbuf2, bn2_g, bn2_b, exp_b, scbi2);

    final_mfma_kernel<<<NOUT_/16, 256, 0, stream>>>(xh, o2h, pool_idx, Ef, scbi2, out);
}